// Round 2
// baseline (667.934 us; speedup 1.0000x reference)
//
#include <hip/hip_runtime.h>

// Problem constants: BS=32, SEQ=2048, IN=512, H=256, L=2
#define SEQL 2048
#define BSZ  32
#define HDIM 256
#define MTOT (BSZ*SEQL)          // 65536 rows
#define XXN  ((size_t)MTOT*512)  // xx output elems

typedef short v8s __attribute__((ext_vector_type(8)));
typedef float v4f __attribute__((ext_vector_type(4)));

// f32 -> bf16 RNE via native cast: compiler emits v_cvt_pk_bf16_f32 pairs.
__device__ __forceinline__ short f2bf(float f) {
  return __builtin_bit_cast(short, (__bf16)f);
}

__device__ __forceinline__ v8s pack8(float4 a, float4 b) {
  v8s r;
  r[0] = f2bf(a.x); r[1] = f2bf(a.y); r[2] = f2bf(a.z); r[3] = f2bf(a.w);
  r[4] = f2bf(b.x); r[5] = f2bf(b.y); r[6] = f2bf(b.z); r[7] = f2bf(b.w);
  return r;
}

// C[m][n] = act( sum_k A[m][k]*W[n][k] + bias[n] ), A row stride sa, W is [256][K],
// C row stride 256. act: 0=none, 1=sigmoid. Tile 128x128, bf16 MFMA.
// Round-1 redesign (latency-bound per rocprof: Mfma 7%, VALU 15%, HBM 28-40%,
// occ 25%, ~3.3K cy per block-K-step = serial HBM round-trips):
//  - 512 threads / 8 waves, per-wave 64x32 tile: acc 32 VGPR, staging 4 f4/thread
//    -> ~128 VGPR -> __launch_bounds__(512,4) -> 2 blocks x 8 waves = 16 waves/CU TLP
//  - 2-deep register prefetch, parity-named reg sets (no runtime-indexed arrays),
//    loop unrolled x2: loads for step k+2 issued at step k -> ~2 sub-steps of flight
//  - raw s_barrier + explicit lgkmcnt(0) (NOT __syncthreads) -> no vmcnt(0) drain
//    at the barrier; only the compiler's counted vmcnt wait at consume time.
// WAR safety (1 barrier/sub-step, 2 LDS buffers): buf b written at sub-step s+2 is
// after barrier(s+1); every wave drains its buf-b ds_reads (our lgkmcnt(0)) before
// signaling barrier(s+1).
__global__ __launch_bounds__(512, 4) void gemm_bias_act(
    const float* __restrict__ A, int sa,
    const float* __restrict__ W, int K,
    const float* __restrict__ bias,
    float* __restrict__ C, int act)
{
  __shared__ short As[2][128*40];   // [128 rows][32 k + 8 pad] shorts, x2 buffers
  __shared__ short Bs[2][128*40];

  int tid  = threadIdx.x;
  int m0   = blockIdx.x * 128;
  int n0   = blockIdx.y * 128;
  int lane = tid & 63;
  int wid  = tid >> 6;          // 0..7
  int wr   = wid >> 2;          // 0..1  (64-row band)
  int wc   = wid & 3;           // 0..3  (32-col band)
  int quad = lane >> 4, r16 = lane & 15;

  int srow = tid >> 2;          // staging row 0..127
  int sq   = tid & 3;           // k-quarter: floats sq*8..sq*8+7

  v4f acc[4][2];
  #pragma unroll
  for (int i = 0; i < 4; ++i)
    #pragma unroll
    for (int j = 0; j < 2; ++j)
      acc[i][j] = (v4f){0.f, 0.f, 0.f, 0.f};

  const float* aB = A + (long)(m0 + srow)*sa + sq*8;
  const float* wB = W + (long)(n0 + srow)*K + sq*8;

  // prologue: issue loads for sub-steps 0 (k=0) and 1 (k=32); K >= 64 always
  float4 a0x = ((const float4*)aB)[0],      a0y = ((const float4*)aB)[1];
  float4 b0x = ((const float4*)wB)[0],      b0y = ((const float4*)wB)[1];
  float4 a1x = ((const float4*)(aB+32))[0], a1y = ((const float4*)(aB+32))[1];
  float4 b1x = ((const float4*)(wB+32))[0], b1y = ((const float4*)(wB+32))[1];

  auto compute = [&](const short* Asb, const short* Bsb) {
    v8s af[4], bfv[2];
    #pragma unroll
    for (int i = 0; i < 4; ++i)
      af[i] = *(const v8s*)&Asb[(wr*64 + i*16 + r16)*40 + quad*8];
    #pragma unroll
    for (int j = 0; j < 2; ++j)
      bfv[j] = *(const v8s*)&Bsb[(wc*32 + j*16 + r16)*40 + quad*8];
    #pragma unroll
    for (int i = 0; i < 4; ++i)
      #pragma unroll
      for (int j = 0; j < 2; ++j)
        acc[i][j] = __builtin_amdgcn_mfma_f32_16x16x32_bf16(af[i], bfv[j], acc[i][j], 0, 0, 0);
  };

  for (int kk = 0; kk < K; kk += 64) {
    // ---- sub-step 0: stage tile kk (parity-0 regs) -> LDS buf 0
    *(v8s*)&As[0][srow*40 + sq*8] = pack8(a0x, a0y);   // counted vmcnt wait here
    *(v8s*)&Bs[0][srow*40 + sq*8] = pack8(b0x, b0y);
    asm volatile("s_waitcnt lgkmcnt(0)" ::: "memory"); // our ds_writes visible
    __builtin_amdgcn_s_barrier();
    {
      int nk = (kk + 64 < K) ? kk + 64 : 0;            // clamp: harmless re-load
      const float4* ap = (const float4*)(aB + nk);
      const float4* wp = (const float4*)(wB + nk);
      a0x = ap[0]; a0y = ap[1]; b0x = wp[0]; b0y = wp[1];
    }
    compute(As[0], Bs[0]);

    // ---- sub-step 1: stage tile kk+32 (parity-1 regs) -> LDS buf 1
    *(v8s*)&As[1][srow*40 + sq*8] = pack8(a1x, a1y);
    *(v8s*)&Bs[1][srow*40 + sq*8] = pack8(b1x, b1y);
    asm volatile("s_waitcnt lgkmcnt(0)" ::: "memory");
    __builtin_amdgcn_s_barrier();
    {
      int nk = (kk + 96 < K) ? kk + 96 : 32;
      const float4* ap = (const float4*)(aB + nk);
      const float4* wp = (const float4*)(wB + nk);
      a1x = ap[0]; a1y = ap[1]; b1x = wp[0]; b1y = wp[1];
    }
    compute(As[1], Bs[1]);
  }

  // Epilogue: C/D layout col=lane&15, row=quad*4+reg
  #pragma unroll
  for (int j = 0; j < 2; ++j) {
    int col = n0 + wc*32 + j*16 + r16;
    float bv = bias[col];
    #pragma unroll
    for (int i = 0; i < 4; ++i) {
      int rowb = m0 + wr*64 + i*16 + quad*4;
      #pragma unroll
      for (int r = 0; r < 4; ++r) {
        float v = acc[i][j][r] + bv;
        if (act) {
          float e = __builtin_amdgcn_exp2f(v * -1.4426950408889634f);
          v = __builtin_amdgcn_rcpf(1.f + e);
        }
        C[(long)(rowb + r)*HDIM + col] = v;
      }
    }
  }
}

// Segment-parallel recurrence: h = tanh(x*(g*h + (1-g)*x)).
// Chain per (dir,b,f) split into 8 time-segments of 256 steps; each segment
// starts h=0 with a 64-step warmup (contraction kills the seed error; see
// round-3 journal). 2048 blocks x 64 thr = 8 waves/CU -> latency hidden by
// TLP (rounds 1-2 proved in-wave pipelining can't fix 1-wave/CU stalls).
// Chain: 4 dep ops/step: tanh(p)=1-2*rcp(e^{2p}+1); r:=rcp(exp2(q)+1);
// q_{t+1}=fma(-2K*a', r, K*(a'+b')), K=2*log2e. r=0.5 <=> h=0. No NaN path.
// Stores batched per 16-step chunk (keeps vmcnt ordering clean).
__global__ __launch_bounds__(64) void recur(
    const float* __restrict__ X, int sx, int xoffR,
    const float* __restrict__ G, int sg, int goffR,
    float* __restrict__ Y, float* __restrict__ hout)
{
  const int T = 16;
  const int SEGS = 8;
  const int SEGLEN = SEQL / SEGS;   // 256
  const int WARM = 64;

  int blk = blockIdx.x & 255;
  int seg = blockIdx.x >> 8;        // 0..7
  int fg = blk & 3;
  int b  = (blk >> 2) & 31;
  int d  = blk >> 7;
  int f  = fg*64 + threadIdx.x;

  int u0    = seg*SEGLEN - (seg ? WARM : 0);   // virtual-time start (incl warmup)
  int warmc = seg ? (WARM/T) : 0;              // 4 or 0 warmup chunks
  int nc    = warmc + SEGLEN/T;                // 20 or 16 chunks
  int half  = nc >> 1;

  int stp  = d ? -1 : 1;
  int t0   = d ? (SEQL-1 - u0) : u0;
  int xoff = d ? xoffR : 0;
  int goff = d ? goffR : 0;

  const float* xc = X + (long)(b*SEQL + t0)*sx + xoff + f;
  const float* gc = G + (long)(b*SEQL + t0)*sg + goff + f;
  long xstep = (long)stp * sx;
  long gstep = (long)stp * sg;

  int ty0 = d ? (SEQL-1 - seg*SEGLEN) : seg*SEGLEN;
  float* yp = Y + (long)(b*SEQL + ty0)*512 + d*HDIM + f;
  long ystep = (long)stp * 512;

  const float K   = 2.8853900817779268f;   // 2*log2(e)
  const float mK2 = -5.7707801635558537f;  // -2K

  float Ax[T], Ag[T], Bx[T], Bg[T], hb[T];
  #pragma unroll
  for (int j = 0; j < T; ++j) { Ax[j] = xc[xstep*j]; Ag[j] = gc[gstep*j]; }

  float r = 0.5f;   // encodes h = 0

  auto compute = [&](float* xb, float* gb) {
    #pragma unroll
    for (int j = 0; j < T; ++j) {
      float x = xb[j], g = gb[j];
      float a = x * g;                       // off-chain
      float m = a * mK2;                     // off-chain
      float n = K * fmaf(x, x - a, a);       // off-chain: K*(a + x^2*(1-g))
      float q = fmaf(m, r, n);               // chain 1
      float E = __builtin_amdgcn_exp2f(q);   // chain 2
      r = __builtin_amdgcn_rcpf(E + 1.0f);   // chain 3+4
      hb[j] = fmaf(-2.0f, r, 1.0f);          // off-chain
    }
  };
  auto flush = [&](int c) {
    if (c >= warmc) {                        // wave-uniform
      #pragma unroll
      for (int j = 0; j < T; ++j) yp[ystep*j] = hb[j];
      yp += ystep*T;
    }
  };

  int c = 0;
  for (int it = 0; it < half; ++it) {
    // prefetch chunk c+1 into B (always valid: c+1 <= nc-1)
    const float* xn = xc + xstep*T;
    const float* gn = gc + gstep*T;
    #pragma unroll
    for (int j = 0; j < T; ++j) { Bx[j] = xn[xstep*j]; Bg[j] = gn[gstep*j]; }
    compute(Ax, Ag); flush(c);
    // prefetch chunk c+2 into A (clamped on last iteration)
    bool hv = (c+2 < nc);
    const float* xn2 = hv ? xn + xstep*T : xn;
    const float* gn2 = hv ? gn + gstep*T : gn;
    #pragma unroll
    for (int j = 0; j < T; ++j) { Ax[j] = xn2[xstep*j]; Ag[j] = gn2[gstep*j]; }
    compute(Bx, Bg); flush(c+1);
    xc = xn2; gc = gn2; c += 2;
  }

  if (seg == SEGS-1)
    hout[(size_t)d*BSZ*HDIM + (size_t)b*HDIM + f] = fmaf(-2.0f, r, 1.0f);
}

extern "C" void kernel_launch(void* const* d_in, const int* in_sizes, int n_in,
                              void* d_out, int out_size, void* d_ws, size_t ws_size,
                              hipStream_t stream) {
  const float* x    = (const float*)d_in[0];
  const float* W_fc = (const float*)d_in[1];
  const float* b_fc = (const float*)d_in[2];
  // d_in[3]=W1, d_in[4]=b1: mathematically dead (blending1 == identity)
  const float* W2   = (const float*)d_in[5];
  const float* b2   = (const float*)d_in[6];

  float* out  = (float*)d_out;
  float* bufA = (float*)d_ws;                      // 64 MiB (l0) / 128 MiB (l1 gates)
  float* bufB = bufA + (size_t)MTOT*HDIM;          // 64 MiB
  float* xx   = out;                               // [32][2048][512]
  float* hout = out + XXN;                         // [4][32][256]

  // H0 = x @ W_fc.T + b_fc            -> bufA  [65536][256]
  gemm_bias_act<<<dim3(512,2), 512, 0, stream>>>(x, 512, W_fc, 512, b_fc, bufA, 0);
  // G0 = sigmoid(H0 @ W2_0.T + b2_0)  -> bufB  (rtl gates = time-flip of same)
  gemm_bias_act<<<dim3(512,2), 512, 0, stream>>>(bufA, HDIM, W2, HDIM, b2, bufB, 1);
  // layer 0 recurrence: X=H0 (both halves of xx equal), writes xx into d_out
  recur<<<2048, 64, 0, stream>>>(bufA, HDIM, 0, bufB, HDIM, 0, xx, hout);
  // layer 1 gates, ONE GEMM: xx flat = [131072][256] rows (ltr/rtl halves are
  // alternating rows, same W2_1) -> bufA as [b][t][2][256]
  gemm_bias_act<<<dim3(1024,2), 512, 0, stream>>>(xx, HDIM, W2 + HDIM*HDIM, HDIM, b2 + HDIM, bufA, 1);
  // layer 1 recurrence, in place in d_out; Gl at +0, Gr at +256, stride 512
  recur<<<2048, 64, 0, stream>>>(xx, 512, 256, bufA, 512, 256, xx, hout + 2*BSZ*HDIM);
}

// Round 5
// 524.875 us; speedup vs baseline: 1.2726x; 1.2726x over previous
//
#include <hip/hip_runtime.h>

// Problem constants: BS=32, SEQ=2048, IN=512, H=256, L=2
#define SEQL 2048
#define BSZ  32
#define HDIM 256
#define MTOT (BSZ*SEQL)          // 65536 rows
#define XXN  ((size_t)MTOT*512)  // xx output elems

typedef short v8s __attribute__((ext_vector_type(8)));
typedef float v4f __attribute__((ext_vector_type(4)));
typedef const __attribute__((address_space(1))) void* gptr_t;
typedef __attribute__((address_space(3))) void* sptr_t;

// f32 -> bf16 RNE via native cast (v_cvt_pk_bf16_f32 pairs).
__device__ __forceinline__ short f2bf(float f) {
  return __builtin_bit_cast(short, (__bf16)f);
}

// Direct global->LDS DMA, 16 B per lane. LDS dest must be wave-uniform base
// (HW adds lane*16); global src is per-lane. Size must be a literal (16).
__device__ __forceinline__ void gload16(const float* g, float* l) {
  __builtin_amdgcn_global_load_lds((gptr_t)g, (sptr_t)l, 16, 0, 0);
}

// C[m][n] = act( sum_k A[m][k]*W[n][k] + bias[n] ), A row stride sa, W is [256][K],
// C row stride 256. act: 0=none, 1=sigmoid. 128x128 tile, 4 waves, 64x64/wave.
//
// Rounds 2-4: m97 structure adapted to f32 inputs. (Rounds 3/4 failed with NO
// timing block => container died at acquire, before any kernel ran: infra.
// Kernel re-audited 3x: uniform barriers, exact-fit LDS/global bounds, WAR-safe,
// bit-identical numerics vs the round-0/1 passing kernel. Resubmitting.)
//  - global_load_lds (16B) stages raw f32 tiles directly into LDS: no VGPR
//    round-trip (round-1 lesson: the allocator kills reg-prefetch). Tile t+1's
//    DMA is issued right after barrier(t) and flies over compute-t; the vmcnt
//    drain at barrier(t+1) is the known ~20% m97 stall, acceptable.
//  - f32 kept in LDS; bf16 conversion at fragment-read (4 cvt_pk/frag, cheap
//    per round-0 measurement). Same cvt order -> bit-identical C.
//  - XOR granule swizzle (rule #21, both-sides-or-neither): LDS dest linear
//    (DMA requires), per-lane GLOBAL source pre-swizzled, ds_read applies the
//    same XOR. Granule g of row r sits at LDS granule g^(r&7): each 16-lane
//    quad hits 8 granule groups x 2 rows = 2 lanes/bank = free (m136).
//    Without it the 128B row stride is a 16-way conflict (5.7x, m136).
// LDS: 2 buf x (A 16KB | B 16KB) = 64 KiB -> 2 blocks/CU, 8 waves/CU.
// WAR safety, 1 barrier/K-step, 2 buffers: tile t+2's DMA into buf[t&1] is
// issued only after barrier(t+1); every wave's ds_reads of buf[t&1] are drained
// (lgkmcnt at __syncthreads) before it signals barrier(t+1).
__global__ __launch_bounds__(256) void gemm_bias_act(
    const float* __restrict__ A, int sa,
    const float* __restrict__ W, int K,
    const float* __restrict__ bias,
    float* __restrict__ C, int act)
{
  __shared__ float lds[16384];   // [2 buf][A 4096 | B 4096] floats = 64 KiB

  int tid  = threadIdx.x;
  int m0   = blockIdx.x * 128;
  int n0   = blockIdx.y * 128;
  int lane = tid & 63;
  int w    = tid >> 6;          // wave 0..3
  int wr   = w >> 1, wc = w & 1;
  int quad = lane >> 4, r16 = lane & 15;

  // ---- staging geometry: inst i (0..3) of wave w covers rows i*32 + w*8 + lrow,
  // LDS float base = buf*8192 + (A?0:4096) + i*1024 + w*256 (wave-uniform),
  // lane writes floats base + lane*4. Row r&7 == lrow. Source granule
  // js = (lane&7) ^ lrow implements the swizzle.
  int lrow = lane >> 3;                 // 0..7
  int js   = (lane & 7) ^ lrow;         // pre-swizzled source granule
  const float* aSrc = A + (long)(m0 + w*8 + lrow)*sa + js*4;
  const float* wSrc = W + (long)(n0 + w*8 + lrow)*K  + js*4;
  float* ldsA = lds + w*256;
  float* ldsB = lds + 4096 + w*256;

  auto stage = [&](int buf, int kk) {
    const float* a = aSrc + kk;
    const float* b = wSrc + kk;
    float* la = ldsA + buf*8192;
    float* lb = ldsB + buf*8192;
    #pragma unroll
    for (int i = 0; i < 4; ++i) {
      gload16(a + (long)i*32*sa, la + i*1024);
      gload16(b + (long)i*32*K,  lb + i*1024);
    }
  };

  // ---- fragment read offsets (constant per thread; swizzled): row r, source
  // granules 2q, 2q+1 live at LDS granules (2q)^(r&7), (2q+1)^(r&7).
  int aoff[4][2], boff[4][2];
  #pragma unroll
  for (int i = 0; i < 4; ++i) {
    int ra = wr*64 + i*16 + r16, sA = ra & 7;
    aoff[i][0] = ra*32 + ((2*quad)     ^ sA)*4;
    aoff[i][1] = ra*32 + ((2*quad + 1) ^ sA)*4;
    int rb = wc*64 + i*16 + r16, sB = rb & 7;
    boff[i][0] = rb*32 + ((2*quad)     ^ sB)*4;
    boff[i][1] = rb*32 + ((2*quad + 1) ^ sB)*4;
  }

  auto loadfrag = [&](const float* base, const int* o) {
    float4 f0 = *(const float4*)(base + o[0]);
    float4 f1 = *(const float4*)(base + o[1]);
    v8s r;
    r[0] = f2bf(f0.x); r[1] = f2bf(f0.y); r[2] = f2bf(f0.z); r[3] = f2bf(f0.w);
    r[4] = f2bf(f1.x); r[5] = f2bf(f1.y); r[6] = f2bf(f1.z); r[7] = f2bf(f1.w);
    return r;
  };

  v4f acc[4][4];
  #pragma unroll
  for (int i = 0; i < 4; ++i)
    #pragma unroll
    for (int j = 0; j < 4; ++j)
      acc[i][j] = (v4f){0.f, 0.f, 0.f, 0.f};

  stage(0, 0);                 // prologue: tile 0 -> buf 0
  int nt = K >> 5;             // 16 (K=512) or 8 (K=256)
  for (int t = 0; t < nt; ++t) {
    __syncthreads();           // drains tile-t DMA (vmcnt) + prior ds_reads (lgkm)
    if (t + 1 < nt) stage((t + 1) & 1, (t + 1) * 32);   // flies over compute-t
    const float* Ab = lds + (t & 1)*8192;
    const float* Bb = Ab + 4096;
    v8s af[4], bfv[4];
    #pragma unroll
    for (int i = 0; i < 4; ++i) af[i]  = loadfrag(Ab, aoff[i]);
    #pragma unroll
    for (int j = 0; j < 4; ++j) bfv[j] = loadfrag(Bb, boff[j]);
    #pragma unroll
    for (int i = 0; i < 4; ++i)
      #pragma unroll
      for (int j = 0; j < 4; ++j)
        acc[i][j] = __builtin_amdgcn_mfma_f32_16x16x32_bf16(af[i], bfv[j], acc[i][j], 0, 0, 0);
  }

  // Epilogue: C/D layout col=lane&15, row=quad*4+reg (unchanged)
  #pragma unroll
  for (int j = 0; j < 4; ++j) {
    int col = n0 + wc*64 + j*16 + r16;
    float bv = bias[col];
    #pragma unroll
    for (int i = 0; i < 4; ++i) {
      int rowb = m0 + wr*64 + i*16 + quad*4;
      #pragma unroll
      for (int r = 0; r < 4; ++r) {
        float v = acc[i][j][r] + bv;
        if (act) {
          float e = __builtin_amdgcn_exp2f(v * -1.4426950408889634f);
          v = __builtin_amdgcn_rcpf(1.f + e);
        }
        C[(long)(rowb + r)*HDIM + col] = v;
      }
    }
  }
}

// Segment-parallel recurrence: h = tanh(x*(g*h + (1-g)*x)).
// Chain per (dir,b,f) split into 8 time-segments of 256 steps; each segment
// starts h=0 with a 64-step warmup (contraction kills the seed error; see
// round-3 journal). 2048 blocks x 64 thr = 8 waves/CU -> latency hidden by
// TLP (rounds 1-2 proved in-wave pipelining can't fix 1-wave/CU stalls).
// Chain: 4 dep ops/step: tanh(p)=1-2*rcp(e^{2p}+1); r:=rcp(exp2(q)+1);
// q_{t+1}=fma(-2K*a', r, K*(a'+b')), K=2*log2e. r=0.5 <=> h=0. No NaN path.
// Stores batched per 16-step chunk (keeps vmcnt ordering clean).
__global__ __launch_bounds__(64) void recur(
    const float* __restrict__ X, int sx, int xoffR,
    const float* __restrict__ G, int sg, int goffR,
    float* __restrict__ Y, float* __restrict__ hout)
{
  const int T = 16;
  const int SEGS = 8;
  const int SEGLEN = SEQL / SEGS;   // 256
  const int WARM = 64;

  int blk = blockIdx.x & 255;
  int seg = blockIdx.x >> 8;        // 0..7
  int fg = blk & 3;
  int b  = (blk >> 2) & 31;
  int d  = blk >> 7;
  int f  = fg*64 + threadIdx.x;

  int u0    = seg*SEGLEN - (seg ? WARM : 0);   // virtual-time start (incl warmup)
  int warmc = seg ? (WARM/T) : 0;              // 4 or 0 warmup chunks
  int nc    = warmc + SEGLEN/T;                // 20 or 16 chunks
  int half  = nc >> 1;

  int stp  = d ? -1 : 1;
  int t0   = d ? (SEQL-1 - u0) : u0;
  int xoff = d ? xoffR : 0;
  int goff = d ? goffR : 0;

  const float* xc = X + (long)(b*SEQL + t0)*sx + xoff + f;
  const float* gc = G + (long)(b*SEQL + t0)*sg + goff + f;
  long xstep = (long)stp * sx;
  long gstep = (long)stp * sg;

  int ty0 = d ? (SEQL-1 - seg*SEGLEN) : seg*SEGLEN;
  float* yp = Y + (long)(b*SEQL + ty0)*512 + d*HDIM + f;
  long ystep = (long)stp * 512;

  const float K   = 2.8853900817779268f;   // 2*log2(e)
  const float mK2 = -5.7707801635558537f;  // -2K

  float Ax[T], Ag[T], Bx[T], Bg[T], hb[T];
  #pragma unroll
  for (int j = 0; j < T; ++j) { Ax[j] = xc[xstep*j]; Ag[j] = gc[gstep*j]; }

  float r = 0.5f;   // encodes h = 0

  auto compute = [&](float* xb, float* gb) {
    #pragma unroll
    for (int j = 0; j < T; ++j) {
      float x = xb[j], g = gb[j];
      float a = x * g;                       // off-chain
      float m = a * mK2;                     // off-chain
      float n = K * fmaf(x, x - a, a);       // off-chain: K*(a + x^2*(1-g))
      float q = fmaf(m, r, n);               // chain 1
      float E = __builtin_amdgcn_exp2f(q);   // chain 2
      r = __builtin_amdgcn_rcpf(E + 1.0f);   // chain 3+4
      hb[j] = fmaf(-2.0f, r, 1.0f);          // off-chain
    }
  };
  auto flush = [&](int c) {
    if (c >= warmc) {                        // wave-uniform
      #pragma unroll
      for (int j = 0; j < T; ++j) yp[ystep*j] = hb[j];
      yp += ystep*T;
    }
  };

  int c = 0;
  for (int it = 0; it < half; ++it) {
    // prefetch chunk c+1 into B (always valid: c+1 <= nc-1)
    const float* xn = xc + xstep*T;
    const float* gn = gc + gstep*T;
    #pragma unroll
    for (int j = 0; j < T; ++j) { Bx[j] = xn[xstep*j]; Bg[j] = gn[gstep*j]; }
    compute(Ax, Ag); flush(c);
    // prefetch chunk c+2 into A (clamped on last iteration)
    bool hv = (c+2 < nc);
    const float* xn2 = hv ? xn + xstep*T : xn;
    const float* gn2 = hv ? gn + gstep*T : gn;
    #pragma unroll
    for (int j = 0; j < T; ++j) { Ax[j] = xn2[xstep*j]; Ag[j] = gn2[gstep*j]; }
    compute(Bx, Bg); flush(c+1);
    xc = xn2; gc = gn2; c += 2;
  }

  if (seg == SEGS-1)
    hout[(size_t)d*BSZ*HDIM + (size_t)b*HDIM + f] = fmaf(-2.0f, r, 1.0f);
}

extern "C" void kernel_launch(void* const* d_in, const int* in_sizes, int n_in,
                              void* d_out, int out_size, void* d_ws, size_t ws_size,
                              hipStream_t stream) {
  const float* x    = (const float*)d_in[0];
  const float* W_fc = (const float*)d_in[1];
  const float* b_fc = (const float*)d_in[2];
  // d_in[3]=W1, d_in[4]=b1: mathematically dead (blending1 == identity)
  const float* W2   = (const float*)d_in[5];
  const float* b2   = (const float*)d_in[6];

  float* out  = (float*)d_out;
  float* bufA = (float*)d_ws;                      // 64 MiB (l0) / 128 MiB (l1 gates)
  float* bufB = bufA + (size_t)MTOT*HDIM;          // 64 MiB
  float* xx   = out;                               // [32][2048][512]
  float* hout = out + XXN;                         // [4][32][256]

  // H0 = x @ W_fc.T + b_fc            -> bufA  [65536][256]
  gemm_bias_act<<<dim3(512,2), 256, 0, stream>>>(x, 512, W_fc, 512, b_fc, bufA, 0);
  // G0 = sigmoid(H0 @ W2_0.T + b2_0)  -> bufB  (rtl gates = time-flip of same)
  gemm_bias_act<<<dim3(512,2), 256, 0, stream>>>(bufA, HDIM, W2, HDIM, b2, bufB, 1);
  // layer 0 recurrence: X=H0 (both halves of xx equal), writes xx into d_out
  recur<<<2048, 64, 0, stream>>>(bufA, HDIM, 0, bufB, HDIM, 0, xx, hout);
  // layer 1 gates, ONE GEMM: xx flat = [131072][256] rows (ltr/rtl halves are
  // alternating rows, same W2_1) -> bufA as [b][t][2][256]
  gemm_bias_act<<<dim3(1024,2), 256, 0, stream>>>(xx, HDIM, W2 + HDIM*HDIM, HDIM, b2 + HDIM, bufA, 1);
  // layer 1 recurrence, in place in d_out; Gl at +0, Gr at +256, stride 512
  recur<<<2048, 64, 0, stream>>>(xx, 512, 256, bufA, 512, 256, xx, hout + 2*BSZ*HDIM);
}

// Round 6
// 472.376 us; speedup vs baseline: 1.4140x; 1.1111x over previous
//
#include <hip/hip_runtime.h>

// Problem constants: BS=32, SEQ=2048, IN=512, H=256, L=2
#define SEQL 2048
#define BSZ  32
#define HDIM 256
#define MTOT (BSZ*SEQL)          // 65536 rows
#define XXN  ((size_t)MTOT*512)  // xx output elems

typedef short v8s __attribute__((ext_vector_type(8)));
typedef float v4f __attribute__((ext_vector_type(4)));
typedef const __attribute__((address_space(1))) void* gptr_t;
typedef __attribute__((address_space(3))) void* sptr_t;

// f32 -> bf16 RNE via native cast (v_cvt_pk_bf16_f32 pairs).
__device__ __forceinline__ short f2bf(float f) {
  return __builtin_bit_cast(short, (__bf16)f);
}

// Direct global->LDS DMA, 16 B per lane. LDS dest must be wave-uniform base
// (HW adds lane*16); global src is per-lane. Size must be a literal (16).
__device__ __forceinline__ void gload16(const float* g, float* l) {
  __builtin_amdgcn_global_load_lds((gptr_t)g, (sptr_t)l, 16, 0, 0);
}

// C[m][n] = act( sum_k A[m][k]*W[n][k] + bias[n] ), A row stride sa, W is [256][K],
// C row stride 256. act: 0=none, 1=sigmoid. 128x128 tile, 4 waves, 64x64/wave.
//
// Round-6: three staging designs all measured ~90 us with every pipe <40% =>
// stall-bound; the __syncthreads vmcnt(0) drain limits the DMA pipeline to ONE
// compute-phase of flight (guide: the structural m97 stall; fix = T4 counted
// vmcnt, never 0 in-loop, +38-73% isolated).
//  - A triple-buffered (HBM/L3 stream, needs ~2 phases of flight), B=W double-
//    buffered (L2-resident after first blocks, 1 phase suffices): 80 KiB LDS,
//    still 2 blocks/CU.
//  - Per step: s_waitcnt vmcnt(4) (leaves the newest group, A(t+2)'s 4 loads,
//    in flight ACROSS the barrier) + raw s_barrier. FIFO accounting per wave:
//    issue order ... [B(t) x4][A(t+1) x4][B(t+1) x4][A(t+2) x4]; at top of
//    step t+1, vmcnt(4) retires everything but A(t+2). Compiler fences
//    (asm "memory") pin group order and pin mem ops around the barrier
//    (m152-class race guard; ds_reads must not hoist past the barrier).
//  - Last iteration peeled with vmcnt(0).
//  - Grid is 1-D, n-fastest (same-m n-pair adjacent) + bijective XCD chunk
//    swizzle (T1, nwg%8==0): both n-halves of an m-tile run consecutively on
//    the SAME XCD -> A-tile's 2nd read hits that XCD's L2; W L2-resident.
//  - XOR granule swizzle on LDS (rule #21, both-sides): DMA dest linear,
//    per-lane GLOBAL source pre-swizzled, ds_read applies the same XOR ->
//    2 lanes/bank (free, m136). f32 kept in LDS; cvt at fragment read.
// WAR safety (1 barrier/step): A-buf (t+2)%3 was read at step t-1, reads
// retired (lgkmcnt(0) before barrier) before barrier(t); its DMA rewrite is
// issued after barrier(t). B-buf (t+1)&1 likewise read at t-1. Readiness:
// each wave waits its own vmcnt before barrier; barrier publishes all waves'
// DMA completions (LDS is CU-local).
__global__ __launch_bounds__(256) void gemm_bias_act(
    const float* __restrict__ A, int sa,
    const float* __restrict__ W, int K,
    const float* __restrict__ bias,
    float* __restrict__ C, int act)
{
  __shared__ float lds[20480];   // A: 3 bufs x 4096f | B: 2 bufs x 4096f = 80 KiB

  int tid  = threadIdx.x;
  // 1-D grid: virtual id v via bijective XCD chunking (nwg % 8 == 0 by launch),
  // then n-fastest: m = v>>1, nhalf = v&1.
  int nwg = (int)gridDim.x;
  int cpx = nwg >> 3;
  int bid = (int)blockIdx.x;
  int v   = (bid & 7) * cpx + (bid >> 3);
  int m0  = (v >> 1) * 128;
  int n0  = (v & 1) * 128;

  int lane = tid & 63;
  int w    = tid >> 6;          // wave 0..3
  int wr   = w >> 1, wc = w & 1;
  int quad = lane >> 4, r16 = lane & 15;

  // ---- staging geometry: inst i (0..3) of wave w covers rows i*32 + w*8 + lrow,
  // LDS float base = buf*4096 + i*1024 + w*256 (wave-uniform), lane adds 16 B.
  // Source granule js = (lane&7) ^ lrow implements the swizzle.
  int lrow = lane >> 3;                 // 0..7
  int js   = (lane & 7) ^ lrow;         // pre-swizzled source granule
  const float* aSrc = A + (long)(m0 + w*8 + lrow)*sa + js*4;
  const float* wSrc = W + (long)(n0 + w*8 + lrow)*K  + js*4;

  auto stageA = [&](int buf, int kk) {
    const float* a = aSrc + kk;
    float* la = lds + buf*4096 + w*256;
    #pragma unroll
    for (int i = 0; i < 4; ++i) gload16(a + (long)i*32*sa, la + i*1024);
  };
  auto stageB = [&](int buf, int kk) {
    const float* b = wSrc + kk;
    float* lb = lds + 12288 + buf*4096 + w*256;
    #pragma unroll
    for (int i = 0; i < 4; ++i) gload16(b + (long)i*32*K, lb + i*1024);
  };

  // ---- fragment read offsets (constant per thread; swizzled): row r, source
  // granules 2q, 2q+1 live at LDS granules (2q)^(r&7), (2q+1)^(r&7).
  int aoff[4][2], boff[4][2];
  #pragma unroll
  for (int i = 0; i < 4; ++i) {
    int ra_ = wr*64 + i*16 + r16, sA = ra_ & 7;
    aoff[i][0] = ra_*32 + ((2*quad)     ^ sA)*4;
    aoff[i][1] = ra_*32 + ((2*quad + 1) ^ sA)*4;
    int rb_ = wc*64 + i*16 + r16, sB = rb_ & 7;
    boff[i][0] = rb_*32 + ((2*quad)     ^ sB)*4;
    boff[i][1] = rb_*32 + ((2*quad + 1) ^ sB)*4;
  }

  auto loadfrag = [&](const float* base, const int* o) {
    float4 f0 = *(const float4*)(base + o[0]);
    float4 f1 = *(const float4*)(base + o[1]);
    v8s r;
    r[0] = f2bf(f0.x); r[1] = f2bf(f0.y); r[2] = f2bf(f0.z); r[3] = f2bf(f0.w);
    r[4] = f2bf(f1.x); r[5] = f2bf(f1.y); r[6] = f2bf(f1.z); r[7] = f2bf(f1.w);
    return r;
  };

  v4f acc[4][4];
  #pragma unroll
  for (int i = 0; i < 4; ++i)
    #pragma unroll
    for (int j = 0; j < 4; ++j)
      acc[i][j] = (v4f){0.f, 0.f, 0.f, 0.f};

  auto compute = [&](const float* Ab, const float* Bb) {
    v8s af[4], bfv[4];
    #pragma unroll
    for (int i = 0; i < 4; ++i) af[i]  = loadfrag(Ab, aoff[i]);
    #pragma unroll
    for (int j = 0; j < 4; ++j) bfv[j] = loadfrag(Bb, boff[j]);
    #pragma unroll
    for (int i = 0; i < 4; ++i)
      #pragma unroll
      for (int j = 0; j < 4; ++j)
        acc[i][j] = __builtin_amdgcn_mfma_f32_16x16x32_bf16(af[i], bfv[j], acc[i][j], 0, 0, 0);
  };

  // ---- prologue: B(0), A(0), A(1). Group order pinned by compiler fences so
  // per-wave VMEM FIFO is [B0 x4][A0 x4][A1 x4].
  stageB(0, 0);
  asm volatile("" ::: "memory");
  stageA(0, 0);
  asm volatile("" ::: "memory");
  stageA(1, 32);

  int nt = K >> 5;              // 16 (K=512) or 8 (K=256); nt >= 8
  int ra = 0;                   // t % 3 (A read buffer)
  for (int t = 0; t < nt - 1; ++t) {
    // Retire all but the newest 4 VMEM ops (= A(t+2)-to-be or A(t+1) in flight):
    // forces A(t), B(t) complete. lgkmcnt(0): our prior ds_reads retired.
    asm volatile("s_waitcnt vmcnt(4) lgkmcnt(0)" ::: "memory");
    __builtin_amdgcn_s_barrier();
    asm volatile("" ::: "memory");   // no mem op crosses the barrier

    stageB((t + 1) & 1, (t + 1) * 32);
    asm volatile("" ::: "memory");   // keep B(t+1) group older than A(t+2) group
    if (t + 2 < nt) {
      int wb = ra + 2; if (wb >= 3) wb -= 3;
      stageA(wb, (t + 2) * 32);
    }

    compute(lds + ra*4096, lds + 12288 + (t & 1)*4096);
    ra = (ra == 2) ? 0 : ra + 1;
  }
  // peeled last step: drain everything
  asm volatile("s_waitcnt vmcnt(0) lgkmcnt(0)" ::: "memory");
  __builtin_amdgcn_s_barrier();
  asm volatile("" ::: "memory");
  compute(lds + ra*4096, lds + 12288 + ((nt - 1) & 1)*4096);

  // Epilogue: C/D layout col=lane&15, row=quad*4+reg (unchanged)
  #pragma unroll
  for (int j = 0; j < 4; ++j) {
    int col = n0 + wc*64 + j*16 + r16;
    float bv = bias[col];
    #pragma unroll
    for (int i = 0; i < 4; ++i) {
      int rowb = m0 + wr*64 + i*16 + quad*4;
      #pragma unroll
      for (int r = 0; r < 4; ++r) {
        float vv = acc[i][j][r] + bv;
        if (act) {
          float e = __builtin_amdgcn_exp2f(vv * -1.4426950408889634f);
          vv = __builtin_amdgcn_rcpf(1.f + e);
        }
        C[(long)(rowb + r)*HDIM + col] = vv;
      }
    }
  }
}

// Segment-parallel recurrence: h = tanh(x*(g*h + (1-g)*x)).
// Chain per (dir,b,f) split into 8 time-segments of 256 steps; each segment
// starts h=0 with a 64-step warmup (contraction kills the seed error; see
// round-3 journal). 2048 blocks x 64 thr = 8 waves/CU -> latency hidden by
// TLP (rounds 1-2 proved in-wave pipelining can't fix 1-wave/CU stalls).
// Chain: 4 dep ops/step: tanh(p)=1-2*rcp(e^{2p}+1); r:=rcp(exp2(q)+1);
// q_{t+1}=fma(-2K*a', r, K*(a'+b')), K=2*log2e. r=0.5 <=> h=0. No NaN path.
// Stores batched per 16-step chunk (keeps vmcnt ordering clean).
__global__ __launch_bounds__(64) void recur(
    const float* __restrict__ X, int sx, int xoffR,
    const float* __restrict__ G, int sg, int goffR,
    float* __restrict__ Y, float* __restrict__ hout)
{
  const int T = 16;
  const int SEGS = 8;
  const int SEGLEN = SEQL / SEGS;   // 256
  const int WARM = 64;

  int blk = blockIdx.x & 255;
  int seg = blockIdx.x >> 8;        // 0..7
  int fg = blk & 3;
  int b  = (blk >> 2) & 31;
  int d  = blk >> 7;
  int f  = fg*64 + threadIdx.x;

  int u0    = seg*SEGLEN - (seg ? WARM : 0);   // virtual-time start (incl warmup)
  int warmc = seg ? (WARM/T) : 0;              // 4 or 0 warmup chunks
  int nc    = warmc + SEGLEN/T;                // 20 or 16 chunks
  int half  = nc >> 1;

  int stp  = d ? -1 : 1;
  int t0   = d ? (SEQL-1 - u0) : u0;
  int xoff = d ? xoffR : 0;
  int goff = d ? goffR : 0;

  const float* xc = X + (long)(b*SEQL + t0)*sx + xoff + f;
  const float* gc = G + (long)(b*SEQL + t0)*sg + goff + f;
  long xstep = (long)stp * sx;
  long gstep = (long)stp * sg;

  int ty0 = d ? (SEQL-1 - seg*SEGLEN) : seg*SEGLEN;
  float* yp = Y + (long)(b*SEQL + ty0)*512 + d*HDIM + f;
  long ystep = (long)stp * 512;

  const float K   = 2.8853900817779268f;   // 2*log2(e)
  const float mK2 = -5.7707801635558537f;  // -2K

  float Ax[T], Ag[T], Bx[T], Bg[T], hb[T];
  #pragma unroll
  for (int j = 0; j < T; ++j) { Ax[j] = xc[xstep*j]; Ag[j] = gc[gstep*j]; }

  float r = 0.5f;   // encodes h = 0

  auto compute = [&](float* xb, float* gb) {
    #pragma unroll
    for (int j = 0; j < T; ++j) {
      float x = xb[j], g = gb[j];
      float a = x * g;                       // off-chain
      float m = a * mK2;                     // off-chain
      float n = K * fmaf(x, x - a, a);       // off-chain: K*(a + x^2*(1-g))
      float q = fmaf(m, r, n);               // chain 1
      float E = __builtin_amdgcn_exp2f(q);   // chain 2
      r = __builtin_amdgcn_rcpf(E + 1.0f);   // chain 3+4
      hb[j] = fmaf(-2.0f, r, 1.0f);          // off-chain
    }
  };
  auto flush = [&](int c) {
    if (c >= warmc) {                        // wave-uniform
      #pragma unroll
      for (int j = 0; j < T; ++j) yp[ystep*j] = hb[j];
      yp += ystep*T;
    }
  };

  int c = 0;
  for (int it = 0; it < half; ++it) {
    // prefetch chunk c+1 into B (always valid: c+1 <= nc-1)
    const float* xn = xc + xstep*T;
    const float* gn = gc + gstep*T;
    #pragma unroll
    for (int j = 0; j < T; ++j) { Bx[j] = xn[xstep*j]; Bg[j] = gn[gstep*j]; }
    compute(Ax, Ag); flush(c);
    // prefetch chunk c+2 into A (clamped on last iteration)
    bool hv = (c+2 < nc);
    const float* xn2 = hv ? xn + xstep*T : xn;
    const float* gn2 = hv ? gn + gstep*T : gn;
    #pragma unroll
    for (int j = 0; j < T; ++j) { Ax[j] = xn2[xstep*j]; Ag[j] = gn2[gstep*j]; }
    compute(Bx, Bg); flush(c+1);
    xc = xn2; gc = gn2; c += 2;
  }

  if (seg == SEGS-1)
    hout[(size_t)d*BSZ*HDIM + (size_t)b*HDIM + f] = fmaf(-2.0f, r, 1.0f);
}

extern "C" void kernel_launch(void* const* d_in, const int* in_sizes, int n_in,
                              void* d_out, int out_size, void* d_ws, size_t ws_size,
                              hipStream_t stream) {
  const float* x    = (const float*)d_in[0];
  const float* W_fc = (const float*)d_in[1];
  const float* b_fc = (const float*)d_in[2];
  // d_in[3]=W1, d_in[4]=b1: mathematically dead (blending1 == identity)
  const float* W2   = (const float*)d_in[5];
  const float* b2   = (const float*)d_in[6];

  float* out  = (float*)d_out;
  float* bufA = (float*)d_ws;                      // 64 MiB (l0) / 128 MiB (l1 gates)
  float* bufB = bufA + (size_t)MTOT*HDIM;          // 64 MiB
  float* xx   = out;                               // [32][2048][512]
  float* hout = out + XXN;                         // [4][32][256]

  // 1-D grids, nwg % 8 == 0 (required by the XCD chunk swizzle).
  // H0 = x @ W_fc.T + b_fc            -> bufA  [65536][256]
  gemm_bias_act<<<1024, 256, 0, stream>>>(x, 512, W_fc, 512, b_fc, bufA, 0);
  // G0 = sigmoid(H0 @ W2_0.T + b2_0)  -> bufB  (rtl gates = time-flip of same)
  gemm_bias_act<<<1024, 256, 0, stream>>>(bufA, HDIM, W2, HDIM, b2, bufB, 1);
  // layer 0 recurrence: X=H0 (both halves of xx equal), writes xx into d_out
  recur<<<2048, 64, 0, stream>>>(bufA, HDIM, 0, bufB, HDIM, 0, xx, hout);
  // layer 1 gates, ONE GEMM: xx flat = [131072][256] rows (ltr/rtl halves are
  // alternating rows, same W2_1) -> bufA as [b][t][2][256]
  gemm_bias_act<<<2048, 256, 0, stream>>>(xx, HDIM, W2 + HDIM*HDIM, HDIM, b2 + HDIM, bufA, 1);
  // layer 1 recurrence, in place in d_out; Gl at +0, Gr at +256, stride 512
  recur<<<2048, 64, 0, stream>>>(xx, 512, 256, bufA, 512, 256, xx, hout + 2*BSZ*HDIM);
}

// Round 7
// 444.865 us; speedup vs baseline: 1.5014x; 1.0618x over previous
//
#include <hip/hip_runtime.h>

// Problem constants: BS=32, SEQ=2048, IN=512, H=256, L=2
#define SEQL 2048
#define BSZ  32
#define HDIM 256
#define MTOT (BSZ*SEQL)          // 65536 rows
#define XXN  ((size_t)MTOT*512)  // xx output elems

typedef short v8s __attribute__((ext_vector_type(8)));
typedef float v4f __attribute__((ext_vector_type(4)));
typedef const __attribute__((address_space(1))) void* gptr_t;
typedef __attribute__((address_space(3))) void* sptr_t;

// f32 -> bf16 RNE via native cast (v_cvt_pk_bf16_f32 pairs).
__device__ __forceinline__ short f2bf(float f) {
  return __builtin_bit_cast(short, (__bf16)f);
}

// Direct global->LDS DMA, 16 B per lane. LDS dest must be wave-uniform base
// (HW adds lane*16); global src is per-lane. Size must be a literal (16).
__device__ __forceinline__ void gload16(const float* g, float* l) {
  __builtin_amdgcn_global_load_lds((gptr_t)g, (sptr_t)l, 16, 0, 0);
}
__device__ __forceinline__ void gload16s(const unsigned short* g, short* l) {
  __builtin_amdgcn_global_load_lds((gptr_t)g, (sptr_t)l, 16, 0, 0);
}

// One-time weight conversion f32 -> bf16 (same f2bf RNE as the GEMMs used
// in-kernel => downstream MFMA inputs bit-identical). out layout:
// [Wfc 256x512][W2_0 256x256][W2_1 256x256].
__global__ __launch_bounds__(256) void wconv(
    const float* __restrict__ Wfc, const float* __restrict__ W2,
    unsigned short* __restrict__ out)
{
  int i = blockIdx.x*256 + threadIdx.x;
  int stride = 256 * gridDim.x;
  for (int k = i; k < 131072; k += stride) {
    out[k]          = (unsigned short)f2bf(Wfc[k]);
    out[131072 + k] = (unsigned short)f2bf(W2[k]);
  }
}

// ---------------------------------------------------------------------------
// Fused GEMM1+GEMM2 (round 7): one block = 128 rows x full 256 cols.
// Phase 1: H = x @ Wfc^T + bfc (K=512), round-6 counted-vmcnt DMA pipeline
//          (A f32 3-buf, Wfc bf16 2-buf). H written f32 to global (recur0
//          input) AND bf16 into LDS (== bf16(H0), exactly what standalone
//          GEMM2 computed from global H0 -> G0 is BIT-IDENTICAL).
// Phase 2: G = sigmoid(bf16(H) @ W2_0^T + b2) (K=256) straight out of LDS;
//          W2 chunks (bf16, L2-resident; first two prefetched at kernel
//          start into a disjoint LDS region) 3-buffered with counted vmcnt.
// Saves GEMM2's entire dispatch (78us of stall) + its 64MB H0 re-read.
// LDS 128 KiB: A 3x16K [0,48K) | Wfc 2x16K [48,80K) | W2 3x16K [80,128K);
// H (64K, [0,64K)) overlays A+Wfc buf0 AFTER phase-1 reads are barriered.
// XOR granule swizzles (rule #21 both-sides): A/H 8-granule rows ^(r&7)
// (2 lanes/bank, free); bf16 W tiles 4-granule rows ^(n&3) (4-way, 1.58x ok).
// ---------------------------------------------------------------------------
__global__ __launch_bounds__(512, 2) void gemm_fused12(
    const float* __restrict__ A,            // x [65536][512] f32
    const unsigned short* __restrict__ Wfc, // bf16 [256][512]
    const float* __restrict__ bfc,
    const unsigned short* __restrict__ W2b, // bf16 [256][256]
    const float* __restrict__ b2v,
    float* __restrict__ Hglob,              // [65536][256] f32
    float* __restrict__ G)                  // [65536][256] f32 (sigmoid)
{
  __shared__ short smem[65536];   // 128 KiB

  int tid  = threadIdx.x;
  int nwg  = (int)gridDim.x;       // 512 (%8==0)
  int cpx  = nwg >> 3;
  int bid  = (int)blockIdx.x;
  int v    = (bid & 7)*cpx + (bid >> 3);   // bijective XCD chunk swizzle
  int m0   = v * 128;

  int lane = tid & 63;
  int w    = tid >> 6;             // 0..7
  int wr   = w >> 2, wc = w & 3;   // wave tile: rows wr*64, cols wc*64
  int quad = lane >> 4, r16 = lane & 15;
  int lrow = lane >> 3;            // 0..7
  int js   = (lane & 7) ^ lrow;    // pre-swizzled f32 source granule

  // ---- staging sources
  const float* aSrc = A + (long)(m0 + w*16 + lrow)*512 + js*4;            // +i*8 rows
  int csB = (lane & 3) ^ ((lane >> 2) & 3);                               // bf16 src granule
  const unsigned short* fcSrc = Wfc + (long)(w*32 + (lane >> 2))*512 + csB*8;  // +i*16 rows
  const unsigned short* w2Src = W2b + (long)(w*32 + (lane >> 2))*256 + csB*8;

  float* Af  = (float*)smem;            // A bufs: + buf*4096 floats
  short* Bf  = smem + 24576;            // Wfc bufs: + buf*8192 shorts
  short* W2f = smem + 40960;            // W2 bufs: + buf*8192 shorts

  auto stageA1 = [&](int buf, int kk) {
    const float* a = aSrc + kk;
    float* la = Af + buf*4096 + (w*2)*256;
    gload16(a,          la);
    gload16(a + 8*512,  la + 256);
  };
  auto stageB1 = [&](int buf, int kk) {
    const unsigned short* g = fcSrc + kk;
    short* lb = Bf + buf*8192 + (w*2)*512;
    gload16s(g,           lb);
    gload16s(g + 16*512,  lb + 512);
  };
  auto stageW2 = [&](int buf, int kk) {
    const unsigned short* g = w2Src + kk;
    short* lb = W2f + buf*8192 + (w*2)*512;
    gload16s(g,           lb);
    gload16s(g + 16*256,  lb + 512);
  };

  // ---- fragment offsets
  int aoff[4][2], boff[4];
  #pragma unroll
  for (int i = 0; i < 4; ++i) {
    int ra_ = wr*64 + i*16 + r16, s7 = r16 & 7;
    aoff[i][0] = ra_*32 + ((2*quad)     ^ s7)*4;
    aoff[i][1] = ra_*32 + ((2*quad + 1) ^ s7)*4;
  }
  #pragma unroll
  for (int j = 0; j < 4; ++j) {
    int n = wc*64 + j*16 + r16;
    boff[j] = n*32 + ((quad ^ (r16 & 3))*8);
  }

  auto loadfragf = [&](const float* base, const int* o) {
    float4 f0 = *(const float4*)(base + o[0]);
    float4 f1 = *(const float4*)(base + o[1]);
    v8s r;
    r[0] = f2bf(f0.x); r[1] = f2bf(f0.y); r[2] = f2bf(f0.z); r[3] = f2bf(f0.w);
    r[4] = f2bf(f1.x); r[5] = f2bf(f1.y); r[6] = f2bf(f1.z); r[7] = f2bf(f1.w);
    return r;
  };

  v4f acc[4][4];
  #pragma unroll
  for (int i = 0; i < 4; ++i)
    #pragma unroll
    for (int j = 0; j < 4; ++j)
      acc[i][j] = (v4f){0.f, 0.f, 0.f, 0.f};

  auto compute1 = [&](int ab, int bb) {
    const float* Ab = Af + ab*4096;
    const short* Bb = Bf + bb*8192;
    v8s af[4], bv[4];
    #pragma unroll
    for (int i = 0; i < 4; ++i) af[i] = loadfragf(Ab, aoff[i]);
    #pragma unroll
    for (int j = 0; j < 4; ++j) bv[j] = *(const v8s*)&Bb[boff[j]];
    #pragma unroll
    for (int i = 0; i < 4; ++i)
      #pragma unroll
      for (int j = 0; j < 4; ++j)
        acc[i][j] = __builtin_amdgcn_mfma_f32_16x16x32_bf16(af[i], bv[j], acc[i][j], 0, 0, 0);
  };

  // ---- prologue: W2(0),W2(1) (region disjoint from phase-1; retired by the
  // first counted wait, data sits in LDS until phase 2), then Bfc(0),A(0),A(1).
  stageW2(0, 0);  asm volatile("" ::: "memory");
  stageW2(1, 32); asm volatile("" ::: "memory");
  stageB1(0, 0);  asm volatile("" ::: "memory");
  stageA1(0, 0);  asm volatile("" ::: "memory");
  stageA1(1, 32);

  // ---- phase-1 K-loop (nt=16). Invariant at top of t: newest 2 VMEM = A(t+1);
  // vmcnt(2) retires A(t),Bfc(t) (and at t=0 the W2 prefetch pair).
  int ra = 0;
  for (int t = 0; t < 15; ++t) {
    asm volatile("s_waitcnt vmcnt(2) lgkmcnt(0)" ::: "memory");
    __builtin_amdgcn_s_barrier();
    asm volatile("" ::: "memory");
    stageB1((t + 1) & 1, (t + 1)*32);
    asm volatile("" ::: "memory");
    if (t + 2 < 16) { int wb = ra + 2; if (wb >= 3) wb -= 3; stageA1(wb, (t + 2)*32); }
    compute1(ra, t & 1);
    ra = (ra == 2) ? 0 : ra + 1;
  }
  asm volatile("s_waitcnt vmcnt(0) lgkmcnt(0)" ::: "memory");
  __builtin_amdgcn_s_barrier();
  asm volatile("" ::: "memory");
  compute1(ra, 1);   // t=15, buf 15&1=1

  // ---- transition: all phase-1 LDS reads done -> overlay H on [0,64K)
  asm volatile("s_waitcnt lgkmcnt(0)" ::: "memory");
  __builtin_amdgcn_s_barrier();
  asm volatile("" ::: "memory");

  // H epilogue: f32 to global (recur0 input), bf16 to LDS (phase-2 A).
  #pragma unroll
  for (int j = 0; j < 4; ++j) {
    int col = wc*64 + j*16 + r16;
    float bv = bfc[col];
    int colg = col >> 3, cl = col & 7;
    #pragma unroll
    for (int i = 0; i < 4; ++i) {
      int rowl = wr*64 + i*16 + quad*4;
      #pragma unroll
      for (int r = 0; r < 4; ++r) {
        int row = rowl + r;
        float h = acc[i][j][r] + bv;
        smem[row*256 + ((colg ^ (row & 7))*8) + cl] = f2bf(h);
        Hglob[(long)(m0 + row)*HDIM + col] = h;
      }
    }
  }

  // ---- phase 2: G = sigmoid(bf16(H) @ W2^T + b2), K2=256, 8 steps.
  // W2(s) 3-buffered; at top of s, vmcnt(2) leaves W2(s+1) in flight (and at
  // s=0 drains the H stores); barrier publishes H writes (s=0) / W2 DMA.
  v4f acc2[4][4];
  #pragma unroll
  for (int i = 0; i < 4; ++i)
    #pragma unroll
    for (int j = 0; j < 4; ++j)
      acc2[i][j] = (v4f){0.f, 0.f, 0.f, 0.f};

  int rb = 0;
  for (int s = 0; s < 8; ++s) {
    asm volatile("s_waitcnt vmcnt(2) lgkmcnt(0)" ::: "memory");
    __builtin_amdgcn_s_barrier();
    asm volatile("" ::: "memory");
    if (s + 2 < 8) { int wb = rb + 2; if (wb >= 3) wb -= 3; stageW2(wb, (s + 2)*32); }
    const short* Wb = W2f + rb*8192;
    v8s hf[4], wv[4];
    #pragma unroll
    for (int i = 0; i < 4; ++i) {
      int m = wr*64 + i*16 + r16;
      hf[i] = *(const v8s*)&smem[m*256 + (((s*4 + quad) ^ (r16 & 7))*8)];
    }
    #pragma unroll
    for (int j = 0; j < 4; ++j) wv[j] = *(const v8s*)&Wb[boff[j]];
    #pragma unroll
    for (int i = 0; i < 4; ++i)
      #pragma unroll
      for (int j = 0; j < 4; ++j)
        acc2[i][j] = __builtin_amdgcn_mfma_f32_16x16x32_bf16(hf[i], wv[j], acc2[i][j], 0, 0, 0);
    rb = (rb == 2) ? 0 : rb + 1;
  }

  // G epilogue (sigmoid), same layout as before.
  #pragma unroll
  for (int j = 0; j < 4; ++j) {
    int col = wc*64 + j*16 + r16;
    float bv = b2v[col];
    #pragma unroll
    for (int i = 0; i < 4; ++i) {
      int rowb = m0 + wr*64 + i*16 + quad*4;
      #pragma unroll
      for (int r = 0; r < 4; ++r) {
        float vv = acc2[i][j][r] + bv;
        float e = __builtin_amdgcn_exp2f(vv * -1.4426950408889634f);
        vv = __builtin_amdgcn_rcpf(1.f + e);
        G[(long)(rowb + r)*HDIM + col] = vv;
      }
    }
  }
}

// ---------------------------------------------------------------------------
// GEMM3 (round-6 counted-vmcnt structure, B now pre-converted bf16):
// C[m][n] = sigmoid(sum_k A[m][k]*W[n][k] + bias[n]), A f32 stride 256, K=256.
// 128x128 tile, 4 waves. LDS: A f32 3x16K + B bf16 2x8K = 64 KiB -> 2 blk/CU.
// Per step: vmcnt(4) (leaves newest A(t+2) group), barrier, stage B(t+1)(2),
// A(t+2)(4), compute. Peeled last step vmcnt(0). Same numerics as before
// (bf16(W) identical via shared f2bf; k-order unchanged) -> bit-identical.
// ---------------------------------------------------------------------------
__global__ __launch_bounds__(256) void gemm_bias_act(
    const float* __restrict__ A,
    const unsigned short* __restrict__ W,   // bf16 [256][256] (layer-1 W2)
    const float* __restrict__ bias,
    float* __restrict__ C)
{
  __shared__ short smem3[32768];   // A 3x16K [0,48K) | B 2x8K [48K,64K)

  int tid  = threadIdx.x;
  int nwg  = (int)gridDim.x;
  int cpx  = nwg >> 3;
  int bid  = (int)blockIdx.x;
  int v    = (bid & 7)*cpx + (bid >> 3);
  int m0   = (v >> 1) * 128;
  int n0   = (v & 1) * 128;

  int lane = tid & 63;
  int w    = tid >> 6;
  int wr   = w >> 1, wc = w & 1;
  int quad = lane >> 4, r16 = lane & 15;
  int lrow = lane >> 3;
  int js   = (lane & 7) ^ lrow;

  const float* aSrc = A + (long)(m0 + w*8 + lrow)*HDIM + js*4;
  int csB = (lane & 3) ^ ((lane >> 2) & 3);
  const unsigned short* wSrc = W + (long)(n0 + w*32 + (lane >> 2))*HDIM + csB*8;

  float* Af = (float*)smem3;
  short* Bs = smem3 + 24576;

  auto stageA = [&](int buf, int kk) {
    const float* a = aSrc + kk;
    float* la = Af + buf*4096 + w*256;
    #pragma unroll
    for (int i = 0; i < 4; ++i) gload16(a + (long)i*32*HDIM, la + i*1024);
  };
  auto stageB = [&](int buf, int kk) {
    const unsigned short* g = wSrc + kk;
    short* lb = Bs + buf*4096 + w*1024;
    gload16s(g,           lb);
    gload16s(g + 16*HDIM, lb + 512);
  };

  int aoff[4][2], boff[4];
  #pragma unroll
  for (int i = 0; i < 4; ++i) {
    int ra_ = wr*64 + i*16 + r16, s7 = r16 & 7;
    aoff[i][0] = ra_*32 + ((2*quad)     ^ s7)*4;
    aoff[i][1] = ra_*32 + ((2*quad + 1) ^ s7)*4;
  }
  #pragma unroll
  for (int j = 0; j < 4; ++j) {
    int n = wc*64 + j*16 + r16;
    boff[j] = n*32 + ((quad ^ (r16 & 3))*8);
  }

  auto loadfragf = [&](const float* base, const int* o) {
    float4 f0 = *(const float4*)(base + o[0]);
    float4 f1 = *(const float4*)(base + o[1]);
    v8s r;
    r[0] = f2bf(f0.x); r[1] = f2bf(f0.y); r[2] = f2bf(f0.z); r[3] = f2bf(f0.w);
    r[4] = f2bf(f1.x); r[5] = f2bf(f1.y); r[6] = f2bf(f1.z); r[7] = f2bf(f1.w);
    return r;
  };

  v4f acc[4][4];
  #pragma unroll
  for (int i = 0; i < 4; ++i)
    #pragma unroll
    for (int j = 0; j < 4; ++j)
      acc[i][j] = (v4f){0.f, 0.f, 0.f, 0.f};

  auto compute = [&](int ab, int bb) {
    const float* Ab = Af + ab*4096;
    const short* Bb = Bs + bb*4096;
    v8s af[4], bv[4];
    #pragma unroll
    for (int i = 0; i < 4; ++i) af[i] = loadfragf(Ab, aoff[i]);
    #pragma unroll
    for (int j = 0; j < 4; ++j) bv[j] = *(const v8s*)&Bb[boff[j]];
    #pragma unroll
    for (int i = 0; i < 4; ++i)
      #pragma unroll
      for (int j = 0; j < 4; ++j)
        acc[i][j] = __builtin_amdgcn_mfma_f32_16x16x32_bf16(af[i], bv[j], acc[i][j], 0, 0, 0);
  };

  stageB(0, 0);  asm volatile("" ::: "memory");
  stageA(0, 0);  asm volatile("" ::: "memory");
  stageA(1, 32);

  int ra = 0;                     // nt = 8 (K=256)
  for (int t = 0; t < 7; ++t) {
    asm volatile("s_waitcnt vmcnt(4) lgkmcnt(0)" ::: "memory");
    __builtin_amdgcn_s_barrier();
    asm volatile("" ::: "memory");
    stageB((t + 1) & 1, (t + 1)*32);
    asm volatile("" ::: "memory");
    if (t + 2 < 8) { int wb = ra + 2; if (wb >= 3) wb -= 3; stageA(wb, (t + 2)*32); }
    compute(ra, t & 1);
    ra = (ra == 2) ? 0 : ra + 1;
  }
  asm volatile("s_waitcnt vmcnt(0) lgkmcnt(0)" ::: "memory");
  __builtin_amdgcn_s_barrier();
  asm volatile("" ::: "memory");
  compute(ra, 1);

  #pragma unroll
  for (int j = 0; j < 4; ++j) {
    int col = n0 + wc*64 + j*16 + r16;
    float bv = bias[col];
    #pragma unroll
    for (int i = 0; i < 4; ++i) {
      int rowb = m0 + wr*64 + i*16 + quad*4;
      #pragma unroll
      for (int r = 0; r < 4; ++r) {
        float vv = acc[i][j][r] + bv;
        float e = __builtin_amdgcn_exp2f(vv * -1.4426950408889634f);
        vv = __builtin_amdgcn_rcpf(1.f + e);
        C[(long)(rowb + r)*HDIM + col] = vv;
      }
    }
  }
}

// Segment-parallel recurrence: h = tanh(x*(g*h + (1-g)*x)).  (unchanged)
__global__ __launch_bounds__(64) void recur(
    const float* __restrict__ X, int sx, int xoffR,
    const float* __restrict__ G, int sg, int goffR,
    float* __restrict__ Y, float* __restrict__ hout)
{
  const int T = 16;
  const int SEGS = 8;
  const int SEGLEN = SEQL / SEGS;   // 256
  const int WARM = 64;

  int blk = blockIdx.x & 255;
  int seg = blockIdx.x >> 8;        // 0..7
  int fg = blk & 3;
  int b  = (blk >> 2) & 31;
  int d  = blk >> 7;
  int f  = fg*64 + threadIdx.x;

  int u0    = seg*SEGLEN - (seg ? WARM : 0);
  int warmc = seg ? (WARM/T) : 0;
  int nc    = warmc + SEGLEN/T;
  int half  = nc >> 1;

  int stp  = d ? -1 : 1;
  int t0   = d ? (SEQL-1 - u0) : u0;
  int xoff = d ? xoffR : 0;
  int goff = d ? goffR : 0;

  const float* xc = X + (long)(b*SEQL + t0)*sx + xoff + f;
  const float* gc = G + (long)(b*SEQL + t0)*sg + goff + f;
  long xstep = (long)stp * sx;
  long gstep = (long)stp * sg;

  int ty0 = d ? (SEQL-1 - seg*SEGLEN) : seg*SEGLEN;
  float* yp = Y + (long)(b*SEQL + ty0)*512 + d*HDIM + f;
  long ystep = (long)stp * 512;

  const float K   = 2.8853900817779268f;   // 2*log2(e)
  const float mK2 = -5.7707801635558537f;  // -2K

  float Ax[T], Ag[T], Bx[T], Bg[T], hb[T];
  #pragma unroll
  for (int j = 0; j < T; ++j) { Ax[j] = xc[xstep*j]; Ag[j] = gc[gstep*j]; }

  float r = 0.5f;   // encodes h = 0

  auto compute = [&](float* xb, float* gb) {
    #pragma unroll
    for (int j = 0; j < T; ++j) {
      float x = xb[j], g = gb[j];
      float a = x * g;
      float m = a * mK2;
      float n = K * fmaf(x, x - a, a);
      float q = fmaf(m, r, n);
      float E = __builtin_amdgcn_exp2f(q);
      r = __builtin_amdgcn_rcpf(E + 1.0f);
      hb[j] = fmaf(-2.0f, r, 1.0f);
    }
  };
  auto flush = [&](int c) {
    if (c >= warmc) {
      #pragma unroll
      for (int j = 0; j < T; ++j) yp[ystep*j] = hb[j];
      yp += ystep*T;
    }
  };

  int c = 0;
  for (int it = 0; it < half; ++it) {
    const float* xn = xc + xstep*T;
    const float* gn = gc + gstep*T;
    #pragma unroll
    for (int j = 0; j < T; ++j) { Bx[j] = xn[xstep*j]; Bg[j] = gn[gstep*j]; }
    compute(Ax, Ag); flush(c);
    bool hv = (c+2 < nc);
    const float* xn2 = hv ? xn + xstep*T : xn;
    const float* gn2 = hv ? gn + gstep*T : gn;
    #pragma unroll
    for (int j = 0; j < T; ++j) { Ax[j] = xn2[xstep*j]; Ag[j] = gn2[gstep*j]; }
    compute(Bx, Bg); flush(c+1);
    xc = xn2; gc = gn2; c += 2;
  }

  if (seg == SEGS-1)
    hout[(size_t)d*BSZ*HDIM + (size_t)b*HDIM + f] = fmaf(-2.0f, r, 1.0f);
}

extern "C" void kernel_launch(void* const* d_in, const int* in_sizes, int n_in,
                              void* d_out, int out_size, void* d_ws, size_t ws_size,
                              hipStream_t stream) {
  const float* x    = (const float*)d_in[0];
  const float* W_fc = (const float*)d_in[1];
  const float* b_fc = (const float*)d_in[2];
  // d_in[3]=W1, d_in[4]=b1: mathematically dead (blending1 == identity)
  const float* W2   = (const float*)d_in[5];
  const float* b2   = (const float*)d_in[6];

  float* out  = (float*)d_out;
  float* bufA = (float*)d_ws;                      // H0 (64 MiB) / l1 gates (128 MiB)
  float* bufB = bufA + (size_t)MTOT*HDIM;          // G0 (64 MiB)
  unsigned short* wbf = (unsigned short*)(bufA + (size_t)50331648); // +192 MiB
  float* xx   = out;                               // [32][2048][512]
  float* hout = out + XXN;                         // [4][32][256]

  // bf16 weight shadows: [Wfc][W2_0][W2_1] (same f2bf RNE as in-kernel => all
  // downstream MFMA inputs bit-identical to previous rounds).
  wconv<<<128, 256, 0, stream>>>(W_fc, W2, wbf);
  // Fused: H0 = x@Wfc^T + bfc -> bufA (f32, recur0 input) and
  //        G0 = sigmoid(bf16(H0)@W2_0^T + b2_0) -> bufB, one dispatch.
  gemm_fused12<<<512, 512, 0, stream>>>(x, wbf, b_fc, wbf + 131072, b2, bufA, bufB);
  // layer 0 recurrence: writes xx into d_out
  recur<<<2048, 64, 0, stream>>>(bufA, HDIM, 0, bufB, HDIM, 0, xx, hout);
  // layer 1 gates, ONE GEMM over xx flat [131072][256]
  gemm_bias_act<<<2048, 256, 0, stream>>>(xx, wbf + 196608, b2 + HDIM, bufA);
  // layer 1 recurrence, in place in d_out
  recur<<<2048, 64, 0, stream>>>(xx, 512, 256, bufA, 512, 256, xx, hout + 2*BSZ*HDIM);
}